// Round 4
// baseline (1628.986 us; speedup 1.0000x reference)
//
#include <hip/hip_runtime.h>
#include <type_traits>

#define DEVINL __device__ __forceinline__

typedef __fp16 f16;
typedef __fp16 f16x2 __attribute__((ext_vector_type(2)));
typedef __fp16 f16x4 __attribute__((ext_vector_type(4)));
typedef __fp16 f16x8 __attribute__((ext_vector_type(8)));

constexpr int Hh = 8;    // hidden size
constexpr int G3 = 24;   // 3*H gate rows
constexpr int TT = 512;  // timesteps

// Activation scales folded into weights/biases at register-load time:
//   sigmoid(v) = rcp(1 + exp2(-log2e * v))
//   tanh(v)    = (1 - e2) * rcp(1 + e2),  e2 = exp2(-2*log2e * v)
constexpr float SNEG  = -1.44269504088896340736f;  // -log2(e)
constexpr float SNEG2 = -2.88539008177792681472f;  // -2*log2(e)

DEVINL float dot2(f16x2 a, f16x2 b, float c) {
#if __has_builtin(__builtin_amdgcn_fdot2)
    return __builtin_amdgcn_fdot2(a, b, c, false);   // v_dot2_f32_f16
#else
    return fmaf((float)a[1], (float)b[1], fmaf((float)a[0], (float)b[0], c));
#endif
}

// xor-8 lane swap within each 32-lane half (BitMode: and=0x1F, or=0, xor=8)
DEVINL float swz8(float v) {
    return __int_as_float(__builtin_amdgcn_ds_swizzle(__float_as_int(v), 0x201F));
}

// Load this lane's k-half of the x row (HALF = IN_DIM/2 elements, one 16B load).
template <typename InT, int IN_DIM>
DEVINL void load_xh(f16x2* d, const InT* p) {
    if constexpr (std::is_same<InT, float>::value) {   // HALF = 4 floats
        float4 v = *(const float4*)p;
        d[0] = __builtin_amdgcn_cvt_pkrtz(v.x, v.y);
        d[1] = __builtin_amdgcn_cvt_pkrtz(v.z, v.w);
    } else {                                           // HALF = 8 f16
        f16x8 v = *(const f16x8*)p;
        d[0] = __builtin_shufflevector(v, v, 0, 1);
        d[1] = __builtin_shufflevector(v, v, 2, 3);
        d[2] = __builtin_shufflevector(v, v, 4, 5);
        d[3] = __builtin_shufflevector(v, v, 6, 7);
    }
}

// One (sequence, direction) unit per SIXTEEN lanes: lane pair (p, p+8) owns
// gate rows {p, 8+p, 16+p}; lo lane computes the low k/j halves, hi lane the
// high halves. Pair reduction via 4x ds_swizzle(xor 8) + add; both lanes then
// redundantly finish the activations and the h update. Doubles the wave count
// (6400 waves = 25/CU) vs the 8-lane layout to hide the serial-chain latency.
template <typename InT, int IN_DIM, bool LAST>
__global__ __launch_bounds__(64, 6) void gru_scan(
    const InT* __restrict__ x,           // (n, T, IN_DIM)
    const float* __restrict__ Wih,       // (2, 24, IN_DIM)
    const float* __restrict__ Whh,       // (2, 24, 8)
    const float* __restrict__ bih,       // (2, 24)
    const float* __restrict__ bhh,       // (2, 24)
    f16* __restrict__ out,               // (n, T, 16): fwd->[0:8], bwd->[8:16]
    float* __restrict__ last,            // (n, 16) only when LAST
    int n)
{
    constexpr int HALF = IN_DIM / 2;     // input elements per lane
    constexpr int QP   = HALF / 2;       // f16x2 words per lane

    const int tid  = threadIdx.x;
    const int u    = tid >> 4;           // unit within block, 0..3
    const int l16  = tid & 15;
    const int p    = l16 & 7;            // pair index = owned gate-row index
    const int hi   = l16 >> 3;           // k/j half selector
    const int unit = blockIdx.x * 4 + u;
    const int dir  = unit >= n ? 1 : 0;  // blocks dir-uniform (n % 4 == 0)
    const int seq  = unit - dir * n;

    const int g0 = p, g1 = 8 + p, g2 = 16 + p;

    // 4 units x 16 f16 slots: slots [0:8) live h, [8:16) hi-lane duplicates
    // (lets all 64 lanes write stride-1 with no predication). Reads: lo lane
    // takes h[0..3] (8B), hi lane h[4..7] -- distinct banks per unit, no
    // conflicts, same-wave lockstep so no barrier needed.
    __shared__ __align__(8) f16 hsh[64];

    // ---- per-lane half-row weights, activation scale pre-folded ----
    const float* Wd = Wih + (size_t)dir * G3 * IN_DIM;
    const int k0 = hi * HALF;
    f16x2 wi0[QP], wi1[QP], wi2[QP];
#pragma unroll
    for (int q = 0; q < QP; ++q) {
        const int k = k0 + 2 * q;
        wi0[q] = __builtin_amdgcn_cvt_pkrtz(Wd[g0 * IN_DIM + k] * SNEG,
                                            Wd[g0 * IN_DIM + k + 1] * SNEG);
        wi1[q] = __builtin_amdgcn_cvt_pkrtz(Wd[g1 * IN_DIM + k] * SNEG,
                                            Wd[g1 * IN_DIM + k + 1] * SNEG);
        wi2[q] = __builtin_amdgcn_cvt_pkrtz(Wd[g2 * IN_DIM + k] * SNEG2,
                                            Wd[g2 * IN_DIM + k + 1] * SNEG2);
    }
    const float* Hd = Whh + (size_t)dir * G3 * Hh;
    const int j0 = hi * 4;
    f16x2 wh0[2], wh1[2], wh2[2];
#pragma unroll
    for (int q = 0; q < 2; ++q) {
        const int j = j0 + 2 * q;
        wh0[q] = __builtin_amdgcn_cvt_pkrtz(Hd[g0 * Hh + j] * SNEG,
                                            Hd[g0 * Hh + j + 1] * SNEG);
        wh1[q] = __builtin_amdgcn_cvt_pkrtz(Hd[g1 * Hh + j] * SNEG,
                                            Hd[g1 * Hh + j + 1] * SNEG);
        wh2[q] = __builtin_amdgcn_cvt_pkrtz(Hd[g2 * Hh + j] * SNEG2,
                                            Hd[g2 * Hh + j + 1] * SNEG2);
    }
    // biases seeded on lo lane only (pair-sum must count them once)
    const float br  = hi ? 0.f : (bih[dir * G3 + g0] + bhh[dir * G3 + g0]) * SNEG;
    const float bz  = hi ? 0.f : (bih[dir * G3 + g1] + bhh[dir * G3 + g1]) * SNEG;
    const float bxn = hi ? 0.f : bih[dir * G3 + g2] * SNEG2;
    const float bhn = hi ? 0.f : bhh[dir * G3 + g2] * SNEG2;

    f16x2 h2[2];                         // this lane's 4-element hidden half
    h2[0] = f16x2{(f16)0.f, (f16)0.f};
    h2[1] = f16x2{(f16)0.f, (f16)0.f};
    float hown = 0.f;                    // own h component (fp32 chain)

    const int t0 = dir ? (TT - 1) : 0;
    const int xstep = dir ? -IN_DIM : IN_DIM;
    const int ostep = dir ? -16 : 16;
    const InT* xp = x + (size_t)(seq * TT + t0) * IN_DIM + k0;
    f16* op = LAST ? nullptr
                   : out + (size_t)(seq * TT + t0) * 16 + dir * 8 + p;

    // layer-3 backward: only out_b[:, T-1] is consumed = its FIRST step
    const int steps = (LAST && dir) ? 1 : TT;

    f16x2 xa[QP], xb[QP];
    load_xh<InT, IN_DIM>(xa, xp); xp += xstep;
    if (steps > 1) { load_xh<InT, IN_DIM>(xb, xp); xp += xstep; }

#define GRU_STEP(XV, PF)                                                      \
    {                                                                         \
        float sr = br, sz = bz, xn = bxn;                                     \
        _Pragma("unroll")                                                     \
        for (int q = 0; q < QP; ++q) {                                        \
            sr = dot2(wi0[q], XV[q], sr);                                     \
            sz = dot2(wi1[q], XV[q], sz);                                     \
            xn = dot2(wi2[q], XV[q], xn);                                     \
        }                                                                     \
        if (PF) { load_xh<InT, IN_DIM>(XV, xp); xp += xstep; }                \
        float hn = bhn;                                                       \
        _Pragma("unroll")                                                     \
        for (int q = 0; q < 2; ++q) {                                         \
            sr = dot2(wh0[q], h2[q], sr);                                     \
            sz = dot2(wh1[q], h2[q], sz);                                     \
            hn = dot2(wh2[q], h2[q], hn);                                     \
        }                                                                     \
        sr += swz8(sr); sz += swz8(sz);                                       \
        xn += swz8(xn); hn += swz8(hn);                                       \
        float r  = __builtin_amdgcn_rcpf(1.f + __builtin_amdgcn_exp2f(sr));   \
        float z  = __builtin_amdgcn_rcpf(1.f + __builtin_amdgcn_exp2f(sz));   \
        float vS = fminf(fmaf(r, hn, xn), 60.f);  /* NaN guard */             \
        float e2 = __builtin_amdgcn_exp2f(vS);                                \
        float nn = (1.f - e2) * __builtin_amdgcn_rcpf(1.f + e2);              \
        float hnew = fmaf(z, hown - nn, nn);      /* (1-z)*n + z*h */         \
        hown = hnew;                                                          \
        f16 hf = (f16)hnew;                                                   \
        if (!LAST) { if (!hi) *op = hf; op += ostep; }                        \
        hsh[u * 16 + hi * 8 + p] = hf;                                        \
        __builtin_amdgcn_wave_barrier();                                      \
        f16x4 hv = *(const f16x4*)&hsh[u * 16 + hi * 4];                      \
        h2[0] = __builtin_shufflevector(hv, hv, 0, 1);                        \
        h2[1] = __builtin_shufflevector(hv, hv, 2, 3);                        \
    }

    int s = 0;
    for (; s + 2 < steps; s += 2) {
        GRU_STEP(xa, true);
        GRU_STEP(xb, true);
    }
    GRU_STEP(xa, false);
    if (steps > 1) GRU_STEP(xb, false);
#undef GRU_STEP

    if (LAST && !hi) last[(size_t)seq * 16 + dir * 8 + p] = hown;
}

// last (n,16) fp32 -> lin1(16->8) -> LeakyReLU(0.2) -> lin2(8->8) -> fp32 out
__global__ void head_kernel(const float* __restrict__ last,
                            const float* __restrict__ w1, const float* __restrict__ b1,
                            const float* __restrict__ w2, const float* __restrict__ b2,
                            float* __restrict__ out, int n)
{
    int i = blockIdx.x * blockDim.x + threadIdx.x;
    if (i >= n) return;
    const float* v = last + (size_t)i * 16;
    float h1[8];
#pragma unroll
    for (int j = 0; j < 8; ++j) {
        float a = b1[j];
#pragma unroll
        for (int k = 0; k < 16; ++k) a = fmaf(w1[j * 16 + k], v[k], a);
        h1[j] = a >= 0.f ? a : 0.2f * a;
    }
#pragma unroll
    for (int j = 0; j < 8; ++j) {
        float o = b2[j];
#pragma unroll
        for (int k = 0; k < 8; ++k) o = fmaf(w2[j * 8 + k], h1[k], o);
        out[(size_t)i * 8 + j] = o;
    }
}

extern "C" void kernel_launch(void* const* d_in, const int* in_sizes, int n_in,
                              void* d_out, int out_size, void* d_ws, size_t ws_size,
                              hipStream_t stream)
{
    const float* raw  = (const float*)d_in[0];
    const float* Wih0 = (const float*)d_in[1];
    const float* Whh0 = (const float*)d_in[2];
    const float* bih0 = (const float*)d_in[3];
    const float* bhh0 = (const float*)d_in[4];
    const float* WihR = (const float*)d_in[5];
    const float* WhhR = (const float*)d_in[6];
    const float* bihR = (const float*)d_in[7];
    const float* bhhR = (const float*)d_in[8];
    const float* w1   = (const float*)d_in[9];
    const float* b1   = (const float*)d_in[10];
    const float* w2   = (const float*)d_in[11];
    const float* b2   = (const float*)d_in[12];

    const int n = in_sizes[0] / (TT * Hh);        // 12800 sequences
    const size_t bufE = (size_t)n * TT * 16;      // elements per (n,T,16) buffer
    dim3 blk(64);
    dim3 grid((unsigned)((2 * n) / 4));           // 4 x 16-lane units per wave
    dim3 hblk(256);
    dim3 hgrid((unsigned)((n + 255) / 256));

    // f16 inter-layer buffers feed v_dot2_f32_f16 directly.
    f16* bufA   = (f16*)d_ws;
    f16* bufB   = bufA + bufE;
    float* lastb = (float*)(bufB + bufE);

    gru_scan<float, 8, false><<<grid, blk, 0, stream>>>(
        raw, Wih0, Whh0, bih0, bhh0, bufA, (float*)nullptr, n);
    gru_scan<f16, 16, false><<<grid, blk, 0, stream>>>(
        bufA, WihR + 0 * 2 * G3 * 16, WhhR + 0 * 2 * G3 * 8,
        bihR + 0 * 2 * G3, bhhR + 0 * 2 * G3, bufB, (float*)nullptr, n);
    gru_scan<f16, 16, false><<<grid, blk, 0, stream>>>(
        bufB, WihR + 1 * 2 * G3 * 16, WhhR + 1 * 2 * G3 * 8,
        bihR + 1 * 2 * G3, bhhR + 1 * 2 * G3, bufA, (float*)nullptr, n);
    gru_scan<f16, 16, true><<<grid, blk, 0, stream>>>(
        bufA, WihR + 2 * 2 * G3 * 16, WhhR + 2 * 2 * G3 * 8,
        bihR + 2 * 2 * G3, bhhR + 2 * 2 * G3, (f16*)nullptr, lastb, n);
    head_kernel<<<hgrid, hblk, 0, stream>>>(
        lastb, w1, b1, w2, b2, (float*)d_out, n);
}

// Round 5
// 1374.848 us; speedup vs baseline: 1.1848x; 1.1848x over previous
//
#include <hip/hip_runtime.h>
#include <type_traits>

#define DEVINL __device__ __forceinline__

typedef __fp16 f16;
typedef __fp16 f16x2 __attribute__((ext_vector_type(2)));
typedef __fp16 f16x8 __attribute__((ext_vector_type(8)));

constexpr int Hh = 8;    // hidden size
constexpr int G3 = 24;   // 3*H gate rows
constexpr int TT = 512;  // timesteps

// Activation scales folded into weights/biases at register-load time:
//   sigmoid(v) = rcp(1 + exp2(-log2e * v))
//   tanh(v)    = (1 - e2) * rcp(1 + e2),  e2 = exp2(-2*log2e * v)
constexpr float SNEG  = -1.44269504088896340736f;  // -log2(e)
constexpr float SNEG2 = -2.88539008177792681472f;  // -2*log2(e)

DEVINL float dot2(f16x2 a, f16x2 b, float c) {
#if __has_builtin(__builtin_amdgcn_fdot2)
    return __builtin_amdgcn_fdot2(a, b, c, false);   // v_dot2_f32_f16
#else
    return fmaf((float)a[1], (float)b[1], fmaf((float)a[0], (float)b[0], c));
#endif
}

// Load one x row into f16x2 words. TWO_IN: row = concat(xf[0:8], xb[0:8]).
template <typename InT, bool TWO_IN>
DEVINL void load_x(f16x2* d, const InT* pf, const InT* pb) {
    if constexpr (std::is_same<InT, float>::value) {
        const float4* p4 = (const float4*)pf;          // 8 floats, one source
        float4 v0 = p4[0], v1 = p4[1];
        d[0] = __builtin_amdgcn_cvt_pkrtz(v0.x, v0.y);
        d[1] = __builtin_amdgcn_cvt_pkrtz(v0.z, v0.w);
        d[2] = __builtin_amdgcn_cvt_pkrtz(v1.x, v1.y);
        d[3] = __builtin_amdgcn_cvt_pkrtz(v1.z, v1.w);
    } else {
        f16x8 a = *(const f16x8*)pf;                   // 16B
        d[0] = __builtin_shufflevector(a, a, 0, 1);
        d[1] = __builtin_shufflevector(a, a, 2, 3);
        d[2] = __builtin_shufflevector(a, a, 4, 5);
        d[3] = __builtin_shufflevector(a, a, 6, 7);
        if constexpr (TWO_IN) {
            f16x8 b = *(const f16x8*)pb;               // 16B
            d[4] = __builtin_shufflevector(b, b, 0, 1);
            d[5] = __builtin_shufflevector(b, b, 2, 3);
            d[6] = __builtin_shufflevector(b, b, 4, 5);
            d[7] = __builtin_shufflevector(b, b, 6, 7);
        }
    }
}

// One (sequence, direction) unit per 8 lanes (R3 structure — best so far).
// Lane i owns gate rows {i, 8+i, 16+i}; all projections in f16 v_dot2; the
// own-lane h chain stays fp32. h all-gather: ds_write_b16 + ds_read_b128.
// R5 changes vs R3: (a) 128-thread 2-wave blocks so the full 12.5 waves/CU
// complement is resident in ONE round (64-thread blocks measured at only
// 8/CU residency); (b) per-direction output buffers -> full-line writes,
// kills the 2x WRITE_SIZE amplification. Zero added instructions.
template <typename InT, bool TWO_IN, bool LAST>
__global__ __launch_bounds__(128, 4) void gru_scan(
    const InT* __restrict__ xf,          // (n, T, 8) fwd half (raw rows for L0)
    const InT* __restrict__ xb,          // (n, T, 8) bwd half (null for L0)
    const float* __restrict__ Wih,       // (2, 24, IN_DIM)
    const float* __restrict__ Whh,       // (2, 24, 8)
    const float* __restrict__ bih,       // (2, 24)
    const float* __restrict__ bhh,       // (2, 24)
    f16* __restrict__ outF,              // (n, T, 8) fwd outputs
    f16* __restrict__ outB,              // (n, T, 8) bwd outputs
    float* __restrict__ last,            // (n, 16) only when LAST
    int n)
{
    constexpr int IN_DIM = TWO_IN ? 16 : 8;
    constexpr int QW = IN_DIM / 2;       // f16x2 words per row

    const int tid   = threadIdx.x;
    const int lane8 = tid & 7;
    const int grp   = tid >> 3;          // 16 groups per block
    const int unit  = blockIdx.x * 16 + grp;
    const int dir   = unit >= n ? 1 : 0; // blocks dir-uniform (n % 16 == 0)
    const int seq   = unit - dir * n;

    const int g0 = lane8, g1 = 8 + lane8, g2 = 16 + lane8;

    // 16 groups x 8 f16. Write: 2B/lane stride-1 (2-way = free). Read:
    // ds_read_b128 broadcast per 8-lane group, 8 distinct 16B rows per wave
    // spanning all 32 banks -- conflict-free. Exchange is intra-wave ->
    // wave_barrier (compile-time fence) suffices, no __syncthreads.
    __shared__ __align__(16) f16 hsh[128];
    const int hbase = grp * 8;

    // ---- weights into registers, activation scale pre-folded ----
    const float* Wd = Wih + (size_t)dir * G3 * IN_DIM;
    f16x2 wi0[QW], wi1[QW], wi2[QW];
#pragma unroll
    for (int q = 0; q < QW; ++q) {
        wi0[q] = __builtin_amdgcn_cvt_pkrtz(Wd[g0 * IN_DIM + 2 * q] * SNEG,
                                            Wd[g0 * IN_DIM + 2 * q + 1] * SNEG);
        wi1[q] = __builtin_amdgcn_cvt_pkrtz(Wd[g1 * IN_DIM + 2 * q] * SNEG,
                                            Wd[g1 * IN_DIM + 2 * q + 1] * SNEG);
        wi2[q] = __builtin_amdgcn_cvt_pkrtz(Wd[g2 * IN_DIM + 2 * q] * SNEG2,
                                            Wd[g2 * IN_DIM + 2 * q + 1] * SNEG2);
    }
    const float* Hd = Whh + (size_t)dir * G3 * Hh;
    f16x2 wh0[Hh / 2], wh1[Hh / 2], wh2[Hh / 2];
#pragma unroll
    for (int q = 0; q < Hh / 2; ++q) {
        wh0[q] = __builtin_amdgcn_cvt_pkrtz(Hd[g0 * Hh + 2 * q] * SNEG,
                                            Hd[g0 * Hh + 2 * q + 1] * SNEG);
        wh1[q] = __builtin_amdgcn_cvt_pkrtz(Hd[g1 * Hh + 2 * q] * SNEG,
                                            Hd[g1 * Hh + 2 * q + 1] * SNEG);
        wh2[q] = __builtin_amdgcn_cvt_pkrtz(Hd[g2 * Hh + 2 * q] * SNEG2,
                                            Hd[g2 * Hh + 2 * q + 1] * SNEG2);
    }
    const float br  = (bih[dir * G3 + g0] + bhh[dir * G3 + g0]) * SNEG;
    const float bz  = (bih[dir * G3 + g1] + bhh[dir * G3 + g1]) * SNEG;
    const float bxn = bih[dir * G3 + g2] * SNEG2;
    const float bhn = bhh[dir * G3 + g2] * SNEG2;

    f16x2 h2[Hh / 2];
#pragma unroll
    for (int q = 0; q < Hh / 2; ++q) h2[q] = f16x2{(f16)0.f, (f16)0.f};
    float hown = 0.f;                          // own h element (fp32 chain)

    const int t0 = dir ? (TT - 1) : 0;
    const int xstep = dir ? -8 : 8;            // half-row element stride
    const int ostep = dir ? -8 : 8;
    const InT* xpf = xf + (size_t)(seq * TT + t0) * 8;
    const InT* xpb = TWO_IN ? (xb + (size_t)(seq * TT + t0) * 8)
                            : (const InT*)nullptr;
    f16* op = LAST ? nullptr
                   : (dir ? outB : outF) + (size_t)(seq * TT + t0) * 8 + lane8;

    // layer-3 backward: only out_b[:, T-1] is consumed = its FIRST step
    const int steps = (LAST && dir) ? 1 : TT;

    f16x2 xA[QW], xB[QW];
    load_x<InT, TWO_IN>(xA, xpf, xpb);
    xpf += xstep; if constexpr (TWO_IN) xpb += xstep;
    if (steps > 1) {
        load_x<InT, TWO_IN>(xB, xpf, xpb);
        xpf += xstep; if constexpr (TWO_IN) xpb += xstep;
    }

#define GRU_STEP(XV, PF)                                                      \
    {                                                                         \
        float sr = br, sz = bz, xn = bxn;                                     \
        _Pragma("unroll")                                                     \
        for (int q = 0; q < QW; ++q) {                                        \
            sr = dot2(wi0[q], XV[q], sr);                                     \
            sz = dot2(wi1[q], XV[q], sz);                                     \
            xn = dot2(wi2[q], XV[q], xn);                                     \
        }                                                                     \
        if (PF) {                                                             \
            load_x<InT, TWO_IN>(XV, xpf, xpb);                                \
            xpf += xstep; if constexpr (TWO_IN) xpb += xstep;                 \
        }                                                                     \
        float hn = bhn;                                                       \
        _Pragma("unroll")                                                     \
        for (int q = 0; q < Hh / 2; ++q) {                                    \
            sr = dot2(wh0[q], h2[q], sr);                                     \
            sz = dot2(wh1[q], h2[q], sz);                                     \
            hn = dot2(wh2[q], h2[q], hn);                                     \
        }                                                                     \
        float r  = __builtin_amdgcn_rcpf(1.f + __builtin_amdgcn_exp2f(sr));   \
        float z  = __builtin_amdgcn_rcpf(1.f + __builtin_amdgcn_exp2f(sz));   \
        float vS = fminf(fmaf(r, hn, xn), 60.f);  /* NaN guard */             \
        float e2 = __builtin_amdgcn_exp2f(vS);                                \
        float nn = (1.f - e2) * __builtin_amdgcn_rcpf(1.f + e2);              \
        float hnew = fmaf(z, hown - nn, nn);      /* (1-z)*n + z*h */         \
        hown = hnew;                                                          \
        f16 hf = (f16)hnew;                       /* one cvt: out + LDS */    \
        if (!LAST) { *op = hf; op += ostep; }                                 \
        hsh[hbase + lane8] = hf;                                              \
        __builtin_amdgcn_wave_barrier();                                      \
        f16x8 hv = *(const f16x8*)&hsh[hbase];                                \
        h2[0] = __builtin_shufflevector(hv, hv, 0, 1);                        \
        h2[1] = __builtin_shufflevector(hv, hv, 2, 3);                        \
        h2[2] = __builtin_shufflevector(hv, hv, 4, 5);                        \
        h2[3] = __builtin_shufflevector(hv, hv, 6, 7);                        \
    }

    int s = 0;
    for (; s + 2 < steps; s += 2) {
        GRU_STEP(xA, true);
        GRU_STEP(xB, true);
    }
    GRU_STEP(xA, false);
    if (steps > 1) GRU_STEP(xB, false);
#undef GRU_STEP

    if (LAST) last[(size_t)seq * 16 + dir * 8 + lane8] = hown;
}

// last (n,16) fp32 -> lin1(16->8) -> LeakyReLU(0.2) -> lin2(8->8) -> fp32 out
__global__ void head_kernel(const float* __restrict__ last,
                            const float* __restrict__ w1, const float* __restrict__ b1,
                            const float* __restrict__ w2, const float* __restrict__ b2,
                            float* __restrict__ out, int n)
{
    int i = blockIdx.x * blockDim.x + threadIdx.x;
    if (i >= n) return;
    const float* v = last + (size_t)i * 16;
    float h1[8];
#pragma unroll
    for (int j = 0; j < 8; ++j) {
        float a = b1[j];
#pragma unroll
        for (int k = 0; k < 16; ++k) a = fmaf(w1[j * 16 + k], v[k], a);
        h1[j] = a >= 0.f ? a : 0.2f * a;
    }
#pragma unroll
    for (int j = 0; j < 8; ++j) {
        float o = b2[j];
#pragma unroll
        for (int k = 0; k < 8; ++k) o = fmaf(w2[j * 8 + k], h1[k], o);
        out[(size_t)i * 8 + j] = o;
    }
}

extern "C" void kernel_launch(void* const* d_in, const int* in_sizes, int n_in,
                              void* d_out, int out_size, void* d_ws, size_t ws_size,
                              hipStream_t stream)
{
    const float* raw  = (const float*)d_in[0];
    const float* Wih0 = (const float*)d_in[1];
    const float* Whh0 = (const float*)d_in[2];
    const float* bih0 = (const float*)d_in[3];
    const float* bhh0 = (const float*)d_in[4];
    const float* WihR = (const float*)d_in[5];
    const float* WhhR = (const float*)d_in[6];
    const float* bihR = (const float*)d_in[7];
    const float* bhhR = (const float*)d_in[8];
    const float* w1   = (const float*)d_in[9];
    const float* b1   = (const float*)d_in[10];
    const float* w2   = (const float*)d_in[11];
    const float* b2   = (const float*)d_in[12];

    const int n = in_sizes[0] / (TT * Hh);        // 12800 sequences
    const size_t hbE = (size_t)n * TT * 8;        // elems per (n,T,8) half-buffer
    dim3 blk(128);
    dim3 grid((unsigned)((2 * n) / 16));          // 16 units per 128-thread block
    dim3 hblk(256);
    dim3 hgrid((unsigned)((n + 255) / 256));

    // Per-direction f16 half-buffers: AF/AB and BF/BB (ping-pong), then lastb.
    // Total = 4 * n*T*8 * 2B + n*16*4B = same 420 MB footprint as before.
    f16* AF = (f16*)d_ws;
    f16* AB = AF + hbE;
    f16* BF = AB + hbE;
    f16* BB = BF + hbE;
    float* lastb = (float*)(BB + hbE);

    gru_scan<float, false, false><<<grid, blk, 0, stream>>>(
        raw, (const float*)nullptr, Wih0, Whh0, bih0, bhh0,
        AF, AB, (float*)nullptr, n);
    gru_scan<f16, true, false><<<grid, blk, 0, stream>>>(
        AF, AB, WihR + 0 * 2 * G3 * 16, WhhR + 0 * 2 * G3 * 8,
        bihR + 0 * 2 * G3, bhhR + 0 * 2 * G3, BF, BB, (float*)nullptr, n);
    gru_scan<f16, true, false><<<grid, blk, 0, stream>>>(
        BF, BB, WihR + 1 * 2 * G3 * 16, WhhR + 1 * 2 * G3 * 8,
        bihR + 1 * 2 * G3, bhhR + 1 * 2 * G3, AF, AB, (float*)nullptr, n);
    gru_scan<f16, true, true><<<grid, blk, 0, stream>>>(
        AF, AB, WihR + 2 * 2 * G3 * 16, WhhR + 2 * 2 * G3 * 8,
        bihR + 2 * 2 * G3, bhhR + 2 * 2 * G3,
        (f16*)nullptr, (f16*)nullptr, lastb, n);
    head_kernel<<<hgrid, hblk, 0, stream>>>(
        lastb, w1, b1, w2, b2, (float*)d_out, n);
}